// Round 9
// baseline (92.422 us; speedup 1.0000x reference)
//
#include <hip/hip_runtime.h>

// mask[b, i, j] = (i < len_q[b]) & (j < len_k[b]);  out is int32 (0 / 1)
// B=32, SEQ=2048  ->  out_size = 32*2048*2048 = 134,217,728 ints (512 MiB)
//
// Fire-and-forget store stream: exactly ONE int4 store per thread.
// Block-size gradient probe: 512thr=89.8us, 256thr=84.0us -> try 128thr.
// (R8 bug fix: batch index is idx>>20 — 2^20 int4 per sample, not 2^22.)

constexpr int SEQ = 2048;
constexpr int THREADS = 128;

typedef int int4v __attribute__((ext_vector_type(4)));

__global__ __launch_bounds__(128) void padmask_kernel(
        const int* __restrict__ len_q,
        const int* __restrict__ len_k,
        int* __restrict__ out) {
    const int idx = blockIdx.x * THREADS + threadIdx.x;   // int4 index, 0..2^25-1

    const int b = idx >> 20;                 // 2^20 int4 per batch sample
    const int i = (idx >> 9) & (SEQ - 1);    // row (512 int4 per row)
    const int j = (idx & 511) << 2;          // element column of lane's .x

    const int lq = len_q[b];
    const int lk = len_k[b];
    const bool qv = (i < lq);

    int4v v;
    v.x = (qv && (j + 0) < lk) ? 1 : 0;
    v.y = (qv && (j + 1) < lk) ? 1 : 0;
    v.z = (qv && (j + 2) < lk) ? 1 : 0;
    v.w = (qv && (j + 3) < lk) ? 1 : 0;
    reinterpret_cast<int4v*>(out)[idx] = v;
}

extern "C" void kernel_launch(void* const* d_in, const int* in_sizes, int n_in,
                              void* d_out, int out_size, void* d_ws, size_t ws_size,
                              hipStream_t stream) {
    const int* len_q = (const int*)d_in[0];
    const int* len_k = (const int*)d_in[1];
    int* out = (int*)d_out;

    const int n_int4 = out_size / 4;                 // 33,554,432
    const int blocks = n_int4 / THREADS;             // 262,144

    padmask_kernel<<<blocks, THREADS, 0, stream>>>(len_q, len_k, out);
}

// Round 10
// 87.328 us; speedup vs baseline: 1.0583x; 1.0583x over previous
//
#include <hip/hip_runtime.h>

// mask[b, i, j] = (i < len_q[b]) & (j < len_k[b]);  out is int32 (0 / 1)
// B=32, SEQ=2048  ->  out_size = 32*2048*2048 = 134,217,728 ints (512 MiB)
//
// WINNER config (R6): fire-and-forget store stream, 131072 blocks x 256
// threads, exactly ONE int4 store per thread. Block-size gradient:
// 128thr=92.4us, 256thr=84.0us, 512thr=89.8us -> 256 optimal.
// 84.0us = 6.39 TB/s = 80% of 8 TB/s spec peak (fill kernel: 6.7-6.9 TB/s
// on a 4x larger burst).

constexpr int SEQ = 2048;
constexpr int THREADS = 256;

typedef int int4v __attribute__((ext_vector_type(4)));

__global__ __launch_bounds__(256) void padmask_kernel(
        const int* __restrict__ len_q,
        const int* __restrict__ len_k,
        int* __restrict__ out) {
    const int idx = blockIdx.x * THREADS + threadIdx.x;   // int4 index, 0..2^25-1

    const int b = idx >> 20;                 // 2^20 int4 per batch sample
    const int i = (idx >> 9) & (SEQ - 1);    // row (512 int4 per row)
    const int j = (idx & 511) << 2;          // element column of lane's .x

    const int lq = len_q[b];
    const int lk = len_k[b];
    const bool qv = (i < lq);

    int4v v;
    v.x = (qv && (j + 0) < lk) ? 1 : 0;
    v.y = (qv && (j + 1) < lk) ? 1 : 0;
    v.z = (qv && (j + 2) < lk) ? 1 : 0;
    v.w = (qv && (j + 3) < lk) ? 1 : 0;
    reinterpret_cast<int4v*>(out)[idx] = v;
}

extern "C" void kernel_launch(void* const* d_in, const int* in_sizes, int n_in,
                              void* d_out, int out_size, void* d_ws, size_t ws_size,
                              hipStream_t stream) {
    const int* len_q = (const int*)d_in[0];
    const int* len_k = (const int*)d_in[1];
    int* out = (int*)d_out;

    const int n_int4 = out_size / 4;                 // 33,554,432
    const int blocks = n_int4 / THREADS;             // 131,072

    padmask_kernel<<<blocks, THREADS, 0, stream>>>(len_q, len_k, out);
}